// Round 6
// baseline (107.632 us; speedup 1.0000x reference)
//
#include <hip/hip_runtime.h>

#define PP 16
#define DD 64
#define RR 32
#define KK 64
#define NBT 4096   // B*T

#define LOG2E 1.4426950408889634f
#define LN2   0.6931471805599453f
#define D2_CUT 25.0f   // keep pairs with d2 <= d2min + CUT; error <= omega_max*e^-25*ln2

static __device__ __forceinline__ float fast_log2(float x) { return __builtin_amdgcn_logf(x); }
static __device__ __forceinline__ float fast_exp2(float x) { return __builtin_amdgcn_exp2f(x); }
static __device__ __forceinline__ float fast_rcp(float x)  { return __builtin_amdgcn_rcpf(x); }
static __device__ __forceinline__ float lane_bcast(float x, int lane) {
    return __int_as_float(__builtin_amdgcn_readlane(__float_as_int(x), lane));
}

// Wave-internal phase fence: drains this wave's LDS ops; program order + lgkmcnt(0)
// makes cross-lane LDS writes visible within the wave. No s_barrier needed.
#define WAVE_SYNC() asm volatile("s_waitcnt lgkmcnt(0)" ::: "memory")

// One block, 1024 threads: thread t=(r,s). Stages c into LDS (transposed, padded),
// computes cc[r]=||c_r||^2, finds d2min over r<s, compacts pairs with
// d2 <= d2min+CUT into plist as (omega, int(r*32+s)).
__global__ __launch_bounds__(1024) void prune_kernel(const float* __restrict__ c,
                                                     float* __restrict__ cc,
                                                     int* __restrict__ npairs,
                                                     float2* __restrict__ plist) {
    __shared__ float2 sm_cT2[32 * 33];   // [d2][r], pad 33 -> conflict-free
    __shared__ float red[16];
    __shared__ float dmin_sh;
    __shared__ int cnt;
    const int t = threadIdx.x;

    {
        const float2* c2 = (const float2*)c;
        int rr = t >> 5, d2i = t & 31;
        sm_cT2[d2i * 33 + rr] = c2[t];
    }
    if (t == 0) cnt = 0;
    __syncthreads();

    const int r = t >> 5, s = t & 31;
    const bool active = s > r;
    float d2 = 0.f;
#pragma unroll
    for (int i = 0; i < 32; ++i) {
        float2 ca = sm_cT2[i * 33 + r];
        float2 cb = sm_cT2[i * 33 + s];
        float dx = ca.x - cb.x, dy = ca.y - cb.y;
        d2 = fmaf(dx, dx, d2);
        d2 = fmaf(dy, dy, d2);
    }
    float dm = active ? d2 : 3.4e38f;
#pragma unroll
    for (int off = 32; off > 0; off >>= 1) dm = fminf(dm, __shfl_down(dm, off, 64));
    if ((t & 63) == 0) red[t >> 6] = dm;
    __syncthreads();
    if (t < 64) {
        float v = (t < 16) ? red[t] : 3.4e38f;
#pragma unroll
        for (int off = 8; off > 0; off >>= 1) v = fminf(v, __shfl_down(v, off, 64));
        if (t == 0) dmin_sh = v;
    }
    if (t < RR) {
        float a2 = 0.f;
#pragma unroll
        for (int i = 0; i < 32; ++i) {
            float2 cv = sm_cT2[i * 33 + t];
            a2 = fmaf(cv.x, cv.x, a2);
            a2 = fmaf(cv.y, cv.y, a2);
        }
        cc[t] = a2;
    }
    __syncthreads();
    const float dmin = dmin_sh;
    if (active && d2 <= dmin + D2_CUT) {
        int idx = atomicAdd(&cnt, 1);
        plist[idx] = make_float2(fast_exp2(-d2 * LOG2E), __int_as_float(t));
    }
    __syncthreads();
    if (t == 0) *npairs = cnt;
}

// Wave-per-bt, LDS-pipe-offloaded: m read from GLOBAL (L1 broadcast, vmem pipe)
// instead of LDS; phase-4 mass-broadcast via v_readlane (VALU pipe) instead of
// LDS. Cuts DS ops/wave from ~420 to ~150 (LDS was the binding per-CU pipe).
__global__ __launch_bounds__(256, 3) void sheaf4_kernel(
    const float* __restrict__ m, const float* __restrict__ w,
    const float* __restrict__ p, const float* __restrict__ c,
    const float* __restrict__ cc, const int* __restrict__ npairs,
    const float2* __restrict__ plist, float* __restrict__ partials) {
    __shared__ float2 sm_cT2[32 * 33];                 // 8448 B, shared, read-only
    __shared__ __align__(16) float sm_pl[4][2048];     // 8 KB/wave: pb[r][k]
    __shared__ __align__(16) float sm_scr[4][640];     // 2.5 KB/wave: logits -> exp
    __shared__ float sm_sw4[4][16];                    // 64 B/wave

    const int tid = threadIdx.x;
    const int wv  = tid >> 6;
    const int ln  = tid & 63;
    const int bt  = blockIdx.x * 4 + wv;

    float* pl  = sm_pl[wv];
    float* scr = sm_scr[wv];
    float* swv = sm_sw4[wv];

    const int r_ = ln & 31, h_ = ln >> 5;  // phase 1/3 mapping
    const int k  = ln;                     // phase 4/5 mapping

    // ---- entry prefetches (latency hides under staging + phase 1) ----
    const float* pg_ = p + (size_t)bt * PP * KK + k;
    float pcol[PP];
#pragma unroll
    for (int pi = 0; pi < PP; ++pi) pcol[pi] = pg_[pi * KK];
    const int np = __builtin_amdgcn_readfirstlane(*npairs);
    const float ccr  = cc[r_];
    const float wreg = w[(size_t)bt * PP + (ln >> 2)];  // used by q==0 lanes in ph2

    // ---- stage: cT2 cooperative only (m is NOT staged — read from global in ph1) ----
    {
        const float2* c2 = (const float2*)c;
#pragma unroll
        for (int it = 0; it < 4; ++it) {
            int idx = tid + 256 * it;
            sm_cT2[(idx & 31) * 33 + (idx >> 5)] = c2[idx];
        }
    }
    __syncthreads();  // the ONLY block barrier (cT2 visibility)

    // ---- phase 1: logits[p][r] = 2*m.c - ||c||^2. Lane (h_, r_) does p = h_*8+i.
    //      m from GLOBAL: 2 distinct 16B lines per instr, each address read once
    //      per wave -> L1-served broadcast on the (idle) vmem pipe, no LDS. ----
    {
        const float4* m4g = (const float4*)(m + (size_t)bt * PP * DD);  // [p][16]
        float acc[8] = {0.f, 0.f, 0.f, 0.f, 0.f, 0.f, 0.f, 0.f};
#pragma unroll
        for (int d4 = 0; d4 < 16; ++d4) {
            float2 ca = sm_cT2[(2 * d4) * 33 + r_];
            float2 cb = sm_cT2[(2 * d4 + 1) * 33 + r_];
#pragma unroll
            for (int i = 0; i < 8; ++i) {
                float4 mm = m4g[(h_ * 8 + i) * 16 + d4];
                acc[i] = fmaf(mm.x, ca.x, acc[i]);
                acc[i] = fmaf(mm.y, ca.y, acc[i]);
                acc[i] = fmaf(mm.z, cb.x, acc[i]);
                acc[i] = fmaf(mm.w, cb.y, acc[i]);
            }
        }
#pragma unroll
        for (int i = 0; i < 8; ++i)
            scr[(h_ * 8 + i) * 36 + r_] = fmaf(2.f, acc[i], -ccr);  // [p][36] view
    }
    WAVE_SYNC();

    // ---- phase 2: softmax over r per p. Lane (pq = ln>>2, q = ln&3) owns 8 r's;
    //      4-lane-group reduce via shfl_xor(1,2). ----
    {
        const int pq = ln >> 2, q = ln & 3;
        float4 v0 = *(const float4*)(scr + pq * 36 + q * 8);
        float4 v1 = *(const float4*)(scr + pq * 36 + q * 8 + 4);
        float mx = fmaxf(fmaxf(fmaxf(v0.x, v0.y), fmaxf(v0.z, v0.w)),
                         fmaxf(fmaxf(v1.x, v1.y), fmaxf(v1.z, v1.w)));
        mx = fmaxf(mx, __shfl_xor(mx, 1, 64));
        mx = fmaxf(mx, __shfl_xor(mx, 2, 64));
        v0.x = fast_exp2((v0.x - mx) * LOG2E); v0.y = fast_exp2((v0.y - mx) * LOG2E);
        v0.z = fast_exp2((v0.z - mx) * LOG2E); v0.w = fast_exp2((v0.w - mx) * LOG2E);
        v1.x = fast_exp2((v1.x - mx) * LOG2E); v1.y = fast_exp2((v1.y - mx) * LOG2E);
        v1.z = fast_exp2((v1.z - mx) * LOG2E); v1.w = fast_exp2((v1.w - mx) * LOG2E);
        float ssum = ((v0.x + v0.y) + (v0.z + v0.w)) + ((v1.x + v1.y) + (v1.z + v1.w));
        ssum += __shfl_xor(ssum, 1, 64);
        ssum += __shfl_xor(ssum, 2, 64);
        *(float4*)(scr + pq * 36 + q * 8)     = v0;
        *(float4*)(scr + pq * 36 + q * 8 + 4) = v1;
        if (q == 0) swv[pq] = wreg * fast_rcp(ssum);  // w / sum
    }
    WAVE_SYNC();

    // ---- phase 3: mass[p][r] = e*sw[p]/(tot_r+eps); KEPT IN REGISTERS.
    //      Lane (r_,h_) ends holding ef[i] = mass[h_*8+i][r_], i=0..7. ----
    float ef[8];
    {
        float tot = 0.f;
#pragma unroll
        for (int i = 0; i < 8; ++i) {
            ef[i] = scr[(h_ * 8 + i) * 36 + r_] * swv[h_ * 8 + i];
            tot += ef[i];
        }
        tot += __shfl_xor(tot, 32, 64);  // combine p-halves
        float inv = fast_rcp(tot + 1e-6f);
#pragma unroll
        for (int i = 0; i < 8; ++i) ef[i] *= inv;
    }
    // no LDS round-trip: phase 4 consumes ef via readlane (no sync needed)

    // ---- phase 4: pb[r][k] = sum_p pcol[p]*mass[p][r]. mass[p][r] broadcast via
    //      v_readlane (VALU pipe, SGPR operand to FMA) -> zero DS reads. ----
    {
#pragma unroll
        for (int r = 0; r < 32; ++r) {
            float pb = 0.f;
#pragma unroll
            for (int i = 0; i < 8; ++i) {
                pb = fmaf(lane_bcast(ef[i], r),      pcol[i],     pb);
                pb = fmaf(lane_bcast(ef[i], r + 32), pcol[8 + i], pb);
            }
            pl[r * KK + k] = pb;
        }
    }
    WAVE_SYNC();

    // ---- phase 5: JS over pruned pairs; all 64 lanes (lane = k); 2-pair ILP.
    //      3 logs per pair (np is small), plist wave-uniform -> s_load. ----
    {
        float acc = 0.f;
        int i = 0;
        for (; i + 1 < np; i += 2) {
            float2 e0 = plist[i];
            float2 e1 = plist[i + 1];
            int rs0 = __float_as_int(e0.y);
            int rs1 = __float_as_int(e1.y);
            float pa0 = pl[(rs0 >> 5) * KK + k];
            float pb0 = pl[(rs0 & 31) * KK + k];
            float pa1 = pl[(rs1 >> 5) * KK + k];
            float pb1 = pl[(rs1 & 31) * KK + k];
            float s0 = pa0 + pb0, s1 = pa1 + pb1;
            float t0 = fmaf(pa0, fast_log2(pa0 + 1e-8f),
                       fmaf(pb0, fast_log2(pb0 + 1e-8f),
                            -s0 * fast_log2(fmaf(0.5f, s0, 1e-8f))));
            float t1 = fmaf(pa1, fast_log2(pa1 + 1e-8f),
                       fmaf(pb1, fast_log2(pb1 + 1e-8f),
                            -s1 * fast_log2(fmaf(0.5f, s1, 1e-8f))));
            acc = fmaf(e0.x, t0, acc);
            acc = fmaf(e1.x, t1, acc);
        }
        if (i < np) {
            float2 e = plist[i];
            int rs = __float_as_int(e.y);
            float pa  = pl[(rs >> 5) * KK + k];
            float pbv = pl[(rs & 31) * KK + k];
            float sum = pa + pbv;
            float t = fmaf(pa, fast_log2(pa + 1e-8f),
                      fmaf(pbv, fast_log2(pbv + 1e-8f),
                           -sum * fast_log2(fmaf(0.5f, sum, 1e-8f))));
            acc = fmaf(e.x, t, acc);
        }
#pragma unroll
        for (int off = 32; off > 0; off >>= 1) acc += __shfl_down(acc, off, 64);
        if (k == 0) partials[bt] = acc * (0.5f * LN2 / 496.0f);
    }
}

__global__ __launch_bounds__(256) void reduce_kernel(const float* __restrict__ partials,
                                                     float* __restrict__ out) {
    __shared__ float sred[4];
    const int tid = threadIdx.x;
    const float4* p4 = (const float4*)partials;  // 1024 float4
    float acc = 0.f;
#pragma unroll
    for (int i = 0; i < 4; ++i) {
        float4 v = p4[tid + 256 * i];
        acc += (v.x + v.y) + (v.z + v.w);
    }
#pragma unroll
    for (int off = 32; off > 0; off >>= 1) acc += __shfl_down(acc, off, 64);
    if ((tid & 63) == 0) sred[tid >> 6] = acc;
    __syncthreads();
    if (tid == 0) out[0] = (sred[0] + sred[1]) + (sred[2] + sred[3]);
}

extern "C" void kernel_launch(void* const* d_in, const int* in_sizes, int n_in,
                              void* d_out, int out_size, void* d_ws, size_t ws_size,
                              hipStream_t stream) {
    const float* m = (const float*)d_in[0];
    const float* w = (const float*)d_in[1];
    const float* p = (const float*)d_in[2];
    const float* c = (const float*)d_in[3];
    float* out = (float*)d_out;

    float* wsf      = (float*)d_ws;
    int*   npairs   = (int*)d_ws;            // [0]
    float* cc       = wsf + 64;              // 32 floats @ 256 B
    float2* plist   = (float2*)(wsf + 128);  // up to 496 float2 @ 512 B
    float* partials = wsf + 2048;            // 4096 floats @ 8 KB (16B-aligned)

    prune_kernel<<<1, 1024, 0, stream>>>(c, cc, npairs, plist);
    sheaf4_kernel<<<NBT / 4, 256, 0, stream>>>(m, w, p, c, cc, npairs, plist, partials);
    reduce_kernel<<<1, 256, 0, stream>>>(partials, out);
}

// Round 7
// 102.963 us; speedup vs baseline: 1.0454x; 1.0454x over previous
//
#include <hip/hip_runtime.h>

#define PP 16
#define DD 64
#define RR 32
#define KK 64
#define NBT 4096   // B*T

#define LOG2E 1.4426950408889634f
#define LN2   0.6931471805599453f
#define D2_CUT 25.0f   // keep pairs with d2 <= d2min + CUT; error <= omega_max*e^-25*ln2

static __device__ __forceinline__ float fast_log2(float x) { return __builtin_amdgcn_logf(x); }
static __device__ __forceinline__ float fast_exp2(float x) { return __builtin_amdgcn_exp2f(x); }
static __device__ __forceinline__ float fast_rcp(float x)  { return __builtin_amdgcn_rcpf(x); }

// One block, 1024 threads: thread t=(r,s). Stages c into LDS (transposed, padded),
// finds d2min over r<s, compacts pairs with d2 <= d2min+CUT into plist as
// (omega, int(r*32+s)). cc is no longer produced (sheaf computes ||c_r||^2 inline).
__global__ __launch_bounds__(1024) void prune_kernel(const float* __restrict__ c,
                                                     int* __restrict__ npairs,
                                                     float2* __restrict__ plist) {
    __shared__ float2 sm_cT2[32 * 33];   // [d2][r], pad 33 -> conflict-free
    __shared__ float red[16];
    __shared__ float dmin_sh;
    __shared__ int cnt;
    const int t = threadIdx.x;

    {
        const float2* c2 = (const float2*)c;
        int rr = t >> 5, d2i = t & 31;
        sm_cT2[d2i * 33 + rr] = c2[t];
    }
    if (t == 0) cnt = 0;
    __syncthreads();

    const int r = t >> 5, s = t & 31;
    const bool active = s > r;
    float d2 = 0.f;
#pragma unroll
    for (int i = 0; i < 32; ++i) {
        float2 ca = sm_cT2[i * 33 + r];   // broadcast within half-wave
        float2 cb = sm_cT2[i * 33 + s];   // contiguous, 2-way (free)
        float dx = ca.x - cb.x, dy = ca.y - cb.y;
        d2 = fmaf(dx, dx, d2);
        d2 = fmaf(dy, dy, d2);
    }
    float dm = active ? d2 : 3.4e38f;
#pragma unroll
    for (int off = 32; off > 0; off >>= 1) dm = fminf(dm, __shfl_down(dm, off, 64));
    if ((t & 63) == 0) red[t >> 6] = dm;
    __syncthreads();
    if (t < 64) {
        float v = (t < 16) ? red[t] : 3.4e38f;
#pragma unroll
        for (int off = 8; off > 0; off >>= 1) v = fminf(v, __shfl_down(v, off, 64));
        if (t == 0) dmin_sh = v;
    }
    __syncthreads();
    const float dmin = dmin_sh;
    if (active && d2 <= dmin + D2_CUT) {
        int idx = atomicAdd(&cnt, 1);
        plist[idx] = make_float2(fast_exp2(-d2 * LOG2E), __int_as_float(t));
    }
    __syncthreads();
    if (t == 0) *npairs = cnt;
}

// r4 champion with the LDS-pipe diet:
//  - ph1 m-reads moved to GLOBAL (2-line broadcast, idle vmem pipe; L1 serves
//    waves 2-4); m LDS staging deleted.
//  - c staged as XOR-swizzled float4 rows [r][d4^(r&7)] -> ph1 c-read is 16
//    ds_read_b128/thread at ~4-way (8 bank-group spread) instead of 32 b64.
//  - ||c_r||^2 accumulated inline in ph1 (+4 FMA/iter on loaded data); cc deleted.
// DS instrs/thread ~120 -> ~78; per-CU LDS-pipe model: sheaf ~38 -> ~29 us.
__global__ __launch_bounds__(256) void sheaf2_kernel(
    const float* __restrict__ m, const float* __restrict__ w,
    const float* __restrict__ p, const float* __restrict__ c,
    const int* __restrict__ npairs, const float2* __restrict__ plist,
    float* __restrict__ partials) {
    // Alias zone: sm_pl (phase 4/5, 16 KB) overlaps the swizzled c4 stage
    // (bytes 0-8191, phase 1). Lifetimes barrier-separated.
    __shared__ __align__(16) float2 sm_pl[RR * KK];  // 16384 B
    __shared__ float  sm_mass[PP * 36];              // 2304 B (pad 36: 16B-aligned rows)
    __shared__ float  sm_sw[PP];
    __shared__ float  sred[4];

    const int tid = threadIdx.x;
    const int bt  = blockIdx.x;
    const int kq  = tid & 63;

    // ---- entry prefetch: p column (16 regs) + np; latency hides under stage+ph1 ----
    const float* pg_ = p + (size_t)bt * PP * KK + kq;
    float pcol[PP];
#pragma unroll
    for (int pi = 0; pi < PP; ++pi) pcol[pi] = pg_[pi * KK];
    const int np = __builtin_amdgcn_readfirstlane(*npairs);

    // ---- stage: c as swizzled float4 rows (8 KB); w -> sm_sw. No m staging. ----
    {
        const float4* c4g = (const float4*)c;     // 512 entries: [r][d4]
        float4* c4s = (float4*)sm_pl;
#pragma unroll
        for (int it = 0; it < 2; ++it) {
            int idx = tid + 256 * it;
            int r = idx >> 4, d4 = idx & 15;
            c4s[r * 16 + (d4 ^ (r & 7))] = c4g[idx];   // XOR swizzle: 8-group spread
        }
        if (tid < PP) sm_sw[tid] = w[(size_t)bt * PP + tid];
    }
    __syncthreads();

    // ---- phase 1: logits[p][r] = 2*m.c - ||c||^2 (||m||^2 cancels in softmax).
    //      m from GLOBAL (broadcast, vmem pipe); c from swizzled LDS b128;
    //      ccr accumulated inline (free FMAs on loaded c). ----
    {
        const int r  = tid & 31;
        const int pg = tid >> 5;  // 0..7; handles pi = pg and pg+8
        const float4* m4g = (const float4*)(m + (size_t)bt * PP * DD);  // [p][16]
        const float4* c4s = (const float4*)sm_pl;
        const int rbase = r * 16, rswz = r & 7;
        float acc0 = 0.f, acc1 = 0.f, ccr = 0.f;
#pragma unroll
        for (int d4 = 0; d4 < 16; ++d4) {
            float4 cv = c4s[rbase + (d4 ^ rswz)];
            float4 ma = m4g[pg * 16 + d4];
            float4 mb = m4g[(pg + 8) * 16 + d4];
            ccr  = fmaf(cv.x, cv.x, ccr);  ccr  = fmaf(cv.y, cv.y, ccr);
            ccr  = fmaf(cv.z, cv.z, ccr);  ccr  = fmaf(cv.w, cv.w, ccr);
            acc0 = fmaf(ma.x, cv.x, acc0); acc0 = fmaf(ma.y, cv.y, acc0);
            acc0 = fmaf(ma.z, cv.z, acc0); acc0 = fmaf(ma.w, cv.w, acc0);
            acc1 = fmaf(mb.x, cv.x, acc1); acc1 = fmaf(mb.y, cv.y, acc1);
            acc1 = fmaf(mb.z, cv.z, acc1); acc1 = fmaf(mb.w, cv.w, acc1);
        }
        sm_mass[pg * 36 + r]       = fmaf(2.f, acc0, -ccr);
        sm_mass[(pg + 8) * 36 + r] = fmaf(2.f, acc1, -ccr);
    }
    __syncthreads();

    // ---- phase 2: per-p softmax over r, all 256 threads.
    //      16 lanes per p, 2 r each; shfl_xor reduce within 16-lane groups. ----
    {
        const int pidx = tid >> 4, l = tid & 15;
        float a = sm_mass[pidx * 36 + l];
        float b = sm_mass[pidx * 36 + l + 16];
        float mx = fmaxf(a, b);
#pragma unroll
        for (int off = 8; off > 0; off >>= 1) mx = fmaxf(mx, __shfl_xor(mx, off, 64));
        float ea = fast_exp2((a - mx) * LOG2E);
        float eb = fast_exp2((b - mx) * LOG2E);
        float ssum = ea + eb;
#pragma unroll
        for (int off = 8; off > 0; off >>= 1) ssum += __shfl_xor(ssum, off, 64);
        sm_mass[pidx * 36 + l]      = ea;
        sm_mass[pidx * 36 + l + 16] = eb;
        if (l == 0) sm_sw[pidx] = sm_sw[pidx] * fast_rcp(ssum);  // w / sum
    }
    __syncthreads();

    // ---- phase 3: mass[p][r] = e*sw[p] / (tot_r + eps); one full wave ----
    if (tid < 64) {
        const int r = tid & 31, h = tid >> 5;
        float ef[8];
        float tot = 0.f;
#pragma unroll
        for (int i = 0; i < 8; ++i) {
            ef[i] = sm_mass[(h * 8 + i) * 36 + r] * sm_sw[h * 8 + i];
            tot += ef[i];
        }
        tot += __shfl_xor(tot, 32, 64);
        float inv = fast_rcp(tot + 1e-6f);
#pragma unroll
        for (int i = 0; i < 8; ++i) sm_mass[(h * 8 + i) * 36 + r] = ef[i] * inv;
    }
    __syncthreads();

    // ---- phase 4: pbar[r][k]; store (pb, pb*log2 pb); overwrites c4s (dead) ----
    {
        const int wv = tid >> 6;
        const int r0 = wv * 8;
        float acc[8] = {0.f, 0.f, 0.f, 0.f, 0.f, 0.f, 0.f, 0.f};
#pragma unroll
        for (int pi = 0; pi < PP; ++pi) {
            float4 ma = *(const float4*)&sm_mass[pi * 36 + r0];      // wave-uniform bcast
            float4 mb = *(const float4*)&sm_mass[pi * 36 + r0 + 4];
            acc[0] = fmaf(pcol[pi], ma.x, acc[0]);
            acc[1] = fmaf(pcol[pi], ma.y, acc[1]);
            acc[2] = fmaf(pcol[pi], ma.z, acc[2]);
            acc[3] = fmaf(pcol[pi], ma.w, acc[3]);
            acc[4] = fmaf(pcol[pi], mb.x, acc[4]);
            acc[5] = fmaf(pcol[pi], mb.y, acc[5]);
            acc[6] = fmaf(pcol[pi], mb.z, acc[6]);
            acc[7] = fmaf(pcol[pi], mb.w, acc[7]);
        }
#pragma unroll
        for (int j = 0; j < 8; ++j) {
            float pb = acc[j];
            float l2 = fast_log2(pb + 1e-8f);
            sm_pl[(r0 + j) * KK + kq] = make_float2(pb, pb * l2);
        }
    }
    __syncthreads();

    // ---- phase 5: sum over pruned pairs of omega*[pr*l2pr + ps*l2ps - (pr+ps)*l2(mid)];
    //      plist loads wave-uniform -> s_load; 2 pairs/iter for ILP ----
    {
        const int wv = __builtin_amdgcn_readfirstlane(tid >> 6);
        float acc = 0.f;
        int i = wv;
        for (; i + 4 < np; i += 8) {
            float2 e0 = plist[i];
            float2 e1 = plist[i + 4];
            int rs0 = __float_as_int(e0.y);
            int rs1 = __float_as_int(e1.y);
            float2 a0 = sm_pl[(rs0 >> 5) * KK + kq];
            float2 b0 = sm_pl[(rs0 & 31) * KK + kq];
            float2 a1 = sm_pl[(rs1 >> 5) * KK + kq];
            float2 b1 = sm_pl[(rs1 & 31) * KK + kq];
            float s0 = a0.x + b0.x, t0 = a0.y + b0.y;
            float s1 = a1.x + b1.x, t1 = a1.y + b1.y;
            float lm0 = fast_log2(fmaf(0.5f, s0, 1e-8f));
            float lm1 = fast_log2(fmaf(0.5f, s1, 1e-8f));
            t0 = fmaf(-s0, lm0, t0);
            t1 = fmaf(-s1, lm1, t1);
            acc = fmaf(e0.x, t0, acc);
            acc = fmaf(e1.x, t1, acc);
        }
        if (i < np) {
            float2 e = plist[i];
            int rs = __float_as_int(e.y);
            float2 a = sm_pl[(rs >> 5) * KK + kq];
            float2 b = sm_pl[(rs & 31) * KK + kq];
            float sum = a.x + b.x;
            float t   = a.y + b.y;
            float lm  = fast_log2(fmaf(0.5f, sum, 1e-8f));
            t = fmaf(-sum, lm, t);
            acc = fmaf(e.x, t, acc);
        }
#pragma unroll
        for (int off = 32; off > 0; off >>= 1) acc += __shfl_down(acc, off, 64);
        if (kq == 0) sred[tid >> 6] = acc;
    }
    __syncthreads();
    if (tid == 0) {
        float tot = (sred[0] + sred[1]) + (sred[2] + sred[3]);
        partials[bt] = tot * (0.5f * LN2 / 496.0f);  // plain store, no atomic
    }
}

__global__ __launch_bounds__(256) void reduce_kernel(const float* __restrict__ partials,
                                                     float* __restrict__ out) {
    __shared__ float sred[4];
    const int tid = threadIdx.x;
    const float4* p4 = (const float4*)partials;  // 1024 float4
    float acc = 0.f;
#pragma unroll
    for (int i = 0; i < 4; ++i) {
        float4 v = p4[tid + 256 * i];
        acc += (v.x + v.y) + (v.z + v.w);
    }
#pragma unroll
    for (int off = 32; off > 0; off >>= 1) acc += __shfl_down(acc, off, 64);
    if ((tid & 63) == 0) sred[tid >> 6] = acc;
    __syncthreads();
    if (tid == 0) out[0] = (sred[0] + sred[1]) + (sred[2] + sred[3]);
}

extern "C" void kernel_launch(void* const* d_in, const int* in_sizes, int n_in,
                              void* d_out, int out_size, void* d_ws, size_t ws_size,
                              hipStream_t stream) {
    const float* m = (const float*)d_in[0];
    const float* w = (const float*)d_in[1];
    const float* p = (const float*)d_in[2];
    const float* c = (const float*)d_in[3];
    float* out = (float*)d_out;

    float* wsf      = (float*)d_ws;
    int*   npairs   = (int*)d_ws;            // [0]
    float2* plist   = (float2*)(wsf + 128);  // up to 496 float2 @ 512 B
    float* partials = wsf + 2048;            // 4096 floats @ 8 KB (16B-aligned)

    prune_kernel<<<1, 1024, 0, stream>>>(c, npairs, plist);
    sheaf2_kernel<<<NBT, 256, 0, stream>>>(m, w, p, c, npairs, plist, partials);
    reduce_kernel<<<1, 256, 0, stream>>>(partials, out);
}